// Round 6
// baseline (44.431 us; speedup 1.0000x reference)
//
#include <hip/hip_runtime.h>
#include <math.h>

// MPDO chain via MFMA + pair table + 8-way split with LDS-MFMA merge tree.
//   per b: edge = Pi_t M_t (64x64), M = sum_k A_k (x) B_k; out = log(tr(edge))
//
//  * Pair table (verified R5): P_t = M_{2t}M_{2t+1}; 16 combos/pair -> prep2
//    builds (1/16)*P^T in bf16 MFMA-A-frag layout (4 MB d_ws). Scale
//    (1/16)^32 = 4^-64 -> log += 64*ln4.
//  * Chain recursion (verified R3): X <- P^T X; A-operand = table, B-operand =
//    running X via in-register C->B relayout (cvt_pk_bf16 + permlane32_swap).
//  * R6: 8 waves/block, wave w runs pairs [4w,4w+4) (4 steps), then 3-level
//    merge: writer waves store G^T to LDS as sT[c][p] (f32, stride 68,
//    conflict-free); reader waves build A-frags from sT, B-frags from own acc,
//    16 MFMA: acc := (partner G^T)(own G^T) = (own*partner)^T. Final:
//    transpose-dot of wave0 acc vs wave4's sT + shfl reduce.
//    Serial depth/block: 4 chain + 3 merge steps (vs 17 in R5); 2 blocks/CU
//    (LDS 69.6 KB) = 4 independent chains/SIMD to fill latency.
// Fallback: ws too small -> verified fp32 VALU kernel.

#define NSITES 64
#define NPAIRS 32
#define SSTRIDE 68   // f32 column stride in sT: 68*4B=272 (16B-aligned), 68%32=4

typedef short  s16x8  __attribute__((ext_vector_type(8)));
typedef float  f32x16 __attribute__((ext_vector_type(16)));

union Frag { unsigned int u[4]; s16x8 v; uint4 q; };

// ---------- prep2: (1/16)*P^T for all (pair, combo) — verified R5 ----------
__global__ __launch_bounds__(64)
void mpdo_prep2(const float* __restrict__ T, uint4* __restrict__ Mfp) {
    const int blk = blockIdx.x;              // 32 pairs * 16 combos
    const int pair = blk >> 4, combo = blk & 15;
    const int c0 = combo >> 2, c1 = combo & 3;
    const int ir0 = c0 >> 1, ic0 = c0 & 1, ir1 = c1 >> 1, ic1 = c1 & 1;
    const int lane = threadIdx.x;
    const int site0 = 2 * pair, site1 = 2 * pair + 1;

    __shared__ float sT0[256], sT1[256], sT2[256], sT3[256];
    __shared__ float sPA[16 * 64], sPB[16 * 64];

    *(float4*)&sT0[lane * 4] = *(const float4*)(T + ((size_t)(site0 * 2 + ir0)) * 256 + lane * 4);
    *(float4*)&sT1[lane * 4] = *(const float4*)(T + ((size_t)(site0 * 2 + ic0)) * 256 + lane * 4);
    *(float4*)&sT2[lane * 4] = *(const float4*)(T + ((size_t)(site1 * 2 + ir1)) * 256 + lane * 4);
    *(float4*)&sT3[lane * 4] = *(const float4*)(T + ((size_t)(site1 * 2 + ic1)) * 256 + lane * 4);
    __syncthreads();

    {
        const int i = lane >> 3, j = lane & 7;
        float pa[4][4], pb[4][4];
#pragma unroll
        for (int k = 0; k < 4; ++k)
#pragma unroll
            for (int jp = 0; jp < 4; ++jp) { pa[k][jp] = 0.0f; pb[k][jp] = 0.0f; }
#pragma unroll
        for (int a = 0; a < 8; ++a) {
            float4 x0 = *(const float4*)&sT0[(i * 8 + a) * 4];
            float4 y0 = *(const float4*)&sT2[(a * 8 + j) * 4];
            float4 x1 = *(const float4*)&sT1[(i * 8 + a) * 4];
            float4 y1 = *(const float4*)&sT3[(a * 8 + j) * 4];
            const float xk0[4] = {x0.x, x0.y, x0.z, x0.w};
            const float yj0[4] = {y0.x, y0.y, y0.z, y0.w};
            const float xk1[4] = {x1.x, x1.y, x1.z, x1.w};
            const float yj1[4] = {y1.x, y1.y, y1.z, y1.w};
#pragma unroll
            for (int k = 0; k < 4; ++k)
#pragma unroll
                for (int jp = 0; jp < 4; ++jp) {
                    pa[k][jp] = fmaf(xk0[k], yj0[jp], pa[k][jp]);
                    pb[k][jp] = fmaf(xk1[k], yj1[jp], pb[k][jp]);
                }
        }
#pragma unroll
        for (int k = 0; k < 4; ++k)
#pragma unroll
            for (int jp = 0; jp < 4; ++jp) {
                sPA[(k * 4 + jp) * 64 + lane] = pa[k][jp];
                sPB[(k * 4 + jp) * 64 + lane] = pb[k][jp];
            }
    }
    __syncthreads();

    const int h = lane >> 5, r = lane & 31, m = r & 7, j2 = r >> 3;
    float acc[8][8];
#pragma unroll
    for (int f = 0; f < 8; ++f)
#pragma unroll
        for (int e = 0; e < 8; ++e) acc[f][e] = 0.0f;

#pragma unroll 4
    for (int c = 0; c < 16; ++c) {
        float paf[8], pbe[8];
#pragma unroll
        for (int ti = 0; ti < 2; ++ti)
#pragma unroll
            for (int kt = 0; kt < 4; ++kt)
                paf[ti * 4 + kt] = sPA[c * 64 + (2 * kt + h) * 8 + (4 * ti + j2)];
#pragma unroll
        for (int e = 0; e < 8; ++e) pbe[e] = sPB[c * 64 + e * 8 + m];
#pragma unroll
        for (int f = 0; f < 8; ++f)
#pragma unroll
            for (int e = 0; e < 8; ++e)
                acc[f][e] = fmaf(paf[f], pbe[e], acc[f][e]);
    }

#pragma unroll
    for (int f = 0; f < 8; ++f) {
        unsigned int wds[4];
#pragma unroll
        for (int q = 0; q < 4; ++q) {
            float v0 = acc[f][2 * q]     * 0.0625f;
            float v1 = acc[f][2 * q + 1] * 0.0625f;
            asm("v_cvt_pk_bf16_f32 %0, %1, %2" : "=v"(wds[q]) : "v"(v0), "v"(v1));
        }
        Mfp[((size_t)(pair * 16 + combo) * 8 + f) * 64 + lane] =
            make_uint4(wds[0], wds[1], wds[2], wds[3]);
    }
}

// ---------- helpers ----------
// B-frags (bf16) from own acc (C-layout f32) — verified R3 relayout
__device__ __forceinline__ void make_Bf(const f32x16 acc[2][2], Frag Bf[4][2]) {
#pragma unroll
    for (int rt = 0; rt < 2; ++rt)
#pragma unroll
        for (int ct = 0; ct < 2; ++ct) {
            unsigned int w0[4], w1[4];
#pragma unroll
            for (int q = 0; q < 4; ++q) {
                asm("v_cvt_pk_bf16_f32 %0, %1, %2"
                    : "=v"(w0[q]) : "v"(acc[rt][ct][4 * q + 0]), "v"(acc[rt][ct][4 * q + 1]));
                asm("v_cvt_pk_bf16_f32 %0, %1, %2"
                    : "=v"(w1[q]) : "v"(acc[rt][ct][4 * q + 2]), "v"(acc[rt][ct][4 * q + 3]));
            }
#pragma unroll
            for (int kp = 0; kp < 2; ++kp) {
                unsigned int x0 = w0[2 * kp], y0 = w0[2 * kp + 1];
                asm("v_permlane32_swap_b32 %0, %1" : "+v"(x0), "+v"(y0));
                unsigned int x1 = w1[2 * kp], y1 = w1[2 * kp + 1];
                asm("v_permlane32_swap_b32 %0, %1" : "+v"(x1), "+v"(y1));
                Frag* f = &Bf[2 * rt + kp][ct];
                f->u[0] = x0; f->u[1] = x1; f->u[2] = y0; f->u[3] = y1;
            }
        }
}

// store G^T (C-layout acc) to LDS as sT[c][p] = G^T[p][c]
__device__ __forceinline__ void write_sT(float* sT, const f32x16 acc[2][2],
                                         int col, int hh) {
#pragma unroll
    for (int rt = 0; rt < 2; ++rt)
#pragma unroll
        for (int ct = 0; ct < 2; ++ct)
#pragma unroll
            for (int q = 0; q < 4; ++q) {
                float4 v = make_float4(acc[rt][ct][4 * q + 0], acc[rt][ct][4 * q + 1],
                                       acc[rt][ct][4 * q + 2], acc[rt][ct][4 * q + 3]);
                *(float4*)&sT[(32 * ct + col) * SSTRIDE + 32 * rt + 8 * q + 4 * hh] = v;
            }
}

// acc := (partner G^T from sT) * (own G^T in acc)  [= (own * partner)^T]
__device__ __forceinline__ void merge_mfma(const float* sT, f32x16 acc[2][2], int lane) {
    const int r = lane & 31, h = lane >> 5;
    Frag Bf[4][2];
    make_Bf(acc, Bf);
    Frag Af[2][4];
#pragma unroll
    for (int ti = 0; ti < 2; ++ti)
#pragma unroll
        for (int kt = 0; kt < 4; ++kt) {
            float e[8];
#pragma unroll
            for (int ee = 0; ee < 8; ++ee)
                e[ee] = sT[(16 * kt + 8 * h + ee) * SSTRIDE + 32 * ti + r];
            unsigned int wv[4];
#pragma unroll
            for (int q = 0; q < 4; ++q)
                asm("v_cvt_pk_bf16_f32 %0, %1, %2"
                    : "=v"(wv[q]) : "v"(e[2 * q]), "v"(e[2 * q + 1]));
            Af[ti][kt].u[0] = wv[0]; Af[ti][kt].u[1] = wv[1];
            Af[ti][kt].u[2] = wv[2]; Af[ti][kt].u[3] = wv[3];
        }
#pragma unroll
    for (int ti = 0; ti < 2; ++ti)
#pragma unroll
        for (int tj = 0; tj < 2; ++tj) {
            f32x16 d = {};
#pragma unroll
            for (int kt = 0; kt < 4; ++kt)
                d = __builtin_amdgcn_mfma_f32_32x32x16_bf16(Af[ti][kt].v, Bf[kt][tj].v, d, 0, 0, 0);
            acc[ti][tj] = d;
        }
}

// ---------- main: 8 waves per b, 4 pair-steps each + merge tree ----------
__global__ __launch_bounds__(512, 2)
void mpdo_mfma8(const int* __restrict__ qn, const uint4* __restrict__ Mfp,
                float* __restrict__ out) {
    const int b = blockIdx.x;
    const int w = threadIdx.x >> 6;
    const int lane = threadIdx.x & 63;
    __shared__ float sT[4][64 * SSTRIDE];

    const int* qb = qn + (size_t)b * (2 * NSITES);
    const int pi = lane & 31;   // lane holds combo of pair pi
    const int pc = (qb[2 * pi] << 3) | (qb[64 + 2 * pi] << 2) |
                   (qb[2 * pi + 1] << 1) | (qb[64 + 2 * pi + 1]);
    const int col = lane & 31, hh = lane >> 5;
    const int s0 = 4 * w, sEnd = s0 + 3;

    f32x16 acc[2][2];
#pragma unroll
    for (int rt = 0; rt < 2; ++rt)
#pragma unroll
        for (int ct = 0; ct < 2; ++ct)
#pragma unroll
            for (int g = 0; g < 16; ++g) {
                int row = (g & 3) + 8 * (g >> 2) + 4 * hh;
                acc[rt][ct][g] = (rt == ct && row == col) ? 1.0f : 0.0f;
            }

    Frag A0[2][4], A1[2][4];
    {
        int cfirst = __shfl(pc, s0, 64);
        const uint4* base = Mfp + ((size_t)(s0 * 16 + cfirst)) * 8 * 64 + lane;
#pragma unroll
        for (int ti = 0; ti < 2; ++ti)
#pragma unroll
            for (int kt = 0; kt < 4; ++kt)
                A0[ti][kt].q = base[(ti * 4 + kt) * 64];
    }

#define SITE_BODY(T_, CUR, NXT)                                               \
    {                                                                         \
        int tn = (T_) + 1; if (tn > sEnd) tn = sEnd;                          \
        int cn = __shfl(pc, tn, 64);                                          \
        const uint4* nbase = Mfp + ((size_t)(tn * 16 + cn)) * 8 * 64 + lane;  \
        _Pragma("unroll")                                                     \
        for (int ti = 0; ti < 2; ++ti)                                        \
            _Pragma("unroll")                                                 \
            for (int kt = 0; kt < 4; ++kt)                                    \
                NXT[ti][kt].q = nbase[(ti * 4 + kt) * 64];                    \
        Frag Bf[4][2];                                                        \
        make_Bf(acc, Bf);                                                     \
        _Pragma("unroll")                                                     \
        for (int ti = 0; ti < 2; ++ti)                                        \
            _Pragma("unroll")                                                 \
            for (int tj = 0; tj < 2; ++tj) {                                  \
                f32x16 d = {};                                                \
                _Pragma("unroll")                                             \
                for (int kt = 0; kt < 4; ++kt)                                \
                    d = __builtin_amdgcn_mfma_f32_32x32x16_bf16(              \
                        CUR[ti][kt].v, Bf[kt][tj].v, d, 0, 0, 0);             \
                acc[ti][tj] = d;                                              \
            }                                                                 \
    }

#pragma unroll 1
    for (int t = s0; t < s0 + 4; t += 2) {
        SITE_BODY(t,     A0, A1)
        SITE_BODY(t + 1, A1, A0)
    }
#undef SITE_BODY

    // ---- merge tree: G0..G7 -> tr(G0 G1 ... G7) ----
    // L1: waves 1,3,5,7 write; waves 0,2,4,6 compute (G_w G_{w+1})^T
    if (w & 1) write_sT(sT[w >> 1], acc, col, hh);
    __syncthreads();
    if (!(w & 1)) merge_mfma(sT[w >> 1], acc, lane);
    __syncthreads();
    // L2: waves 2,6 write; waves 0,4 compute 4-chunk products
    if (w == 2 || w == 6) write_sT(sT[w >> 2], acc, col, hh);
    __syncthreads();
    if (w == 0 || w == 4) merge_mfma(sT[w >> 2], acc, lane);
    __syncthreads();
    // L3: wave 4 writes G4..7^T; wave 0 transpose-dots
    if (w == 4) write_sT(sT[0], acc, col, hh);
    __syncthreads();
    if (w == 0) {
        float dot = 0.0f;
#pragma unroll
        for (int rt = 0; rt < 2; ++rt)
#pragma unroll
            for (int ct = 0; ct < 2; ++ct)
#pragma unroll
                for (int g = 0; g < 16; ++g) {
                    int p = 32 * rt + (g & 3) + 8 * (g >> 2) + 4 * hh;
                    dot = fmaf(acc[rt][ct][g], sT[0][p * SSTRIDE + 32 * ct + col], dot);
                }
#pragma unroll
        for (int off = 32; off >= 1; off >>= 1)
            dot += __shfl_xor(dot, off, 64);
        if (lane == 0) {
            float tr = dot;
            float re = logf(fabsf(tr)) + 64.0f * 1.3862943611198906f; // undo 4^-64
            float im = (tr < 0.0f) ? 3.14159265358979323846f : 0.0f;
            out[2 * b]     = re;
            out[2 * b + 1] = im;
        }
    }
}

// ---------- fallback fp32 VALU kernel (verified R2) ----------
#define DD 8
#define KCHI 4
__global__ __launch_bounds__(64, 1)
void mpdo_chain(const int* __restrict__ qn, const float* __restrict__ T,
                float* __restrict__ out) {
    const int b = blockIdx.x;
    const int lane = threadIdx.x;
    __shared__ float sA[KCHI][DD][DD];
    __shared__ float sB[KCHI][DD][DD];
    float E[DD][DD];
#pragma unroll
    for (int i = 0; i < DD; ++i)
#pragma unroll
        for (int l = 0; l < DD; ++l) E[i][l] = (i * DD + l == lane) ? 1.0f : 0.0f;
    const int* qb = qn + (size_t)b * (2 * NSITES);
    int ir0 = qb[0], ic0 = qb[NSITES];
    float4 aP = *reinterpret_cast<const float4*>(T + (size_t)ir0 * 256 + lane * 4);
    float4 bP = *reinterpret_cast<const float4*>(T + (size_t)ic0 * 256 + lane * 4);
    const int li = lane >> 3, lj = lane & 7;
#pragma unroll 1
    for (int site = 0; site < NSITES; ++site) {
        __syncthreads();
        sA[0][li][lj] = 0.5f * aP.x; sA[1][li][lj] = 0.5f * aP.y;
        sA[2][li][lj] = 0.5f * aP.z; sA[3][li][lj] = 0.5f * aP.w;
        sB[0][li][lj] = 0.5f * bP.x; sB[1][li][lj] = 0.5f * bP.y;
        sB[2][li][lj] = 0.5f * bP.z; sB[3][li][lj] = 0.5f * bP.w;
        __syncthreads();
        if (site + 1 < NSITES) {
            int irn = qb[site + 1], icn = qb[NSITES + site + 1];
            aP = *reinterpret_cast<const float4*>(T + ((size_t)(site + 1) * 2 + irn) * 256 + lane * 4);
            bP = *reinterpret_cast<const float4*>(T + ((size_t)(site + 1) * 2 + icn) * 256 + lane * 4);
        }
        float Ep[DD][DD];
#pragma unroll
        for (int j = 0; j < DD; ++j)
#pragma unroll
            for (int m = 0; m < DD; ++m) Ep[j][m] = 0.0f;
#pragma unroll 1
        for (int k = 0; k < KCHI; ++k) {
            float tmp[DD][DD];
#pragma unroll
            for (int l = 0; l < DD; ++l) {
                const float4* bp = reinterpret_cast<const float4*>(&sB[k][l][0]);
                float4 b0 = bp[0], b1 = bp[1];
                float brow[DD] = {b0.x, b0.y, b0.z, b0.w, b1.x, b1.y, b1.z, b1.w};
                if (l == 0) {
#pragma unroll
                    for (int i = 0; i < DD; ++i)
#pragma unroll
                        for (int m = 0; m < DD; ++m) tmp[i][m] = E[i][0] * brow[m];
                } else {
#pragma unroll
                    for (int i = 0; i < DD; ++i)
#pragma unroll
                        for (int m = 0; m < DD; ++m)
                            tmp[i][m] = fmaf(E[i][l], brow[m], tmp[i][m]);
                }
            }
#pragma unroll
            for (int i = 0; i < DD; ++i) {
                const float4* ap = reinterpret_cast<const float4*>(&sA[k][i][0]);
                float4 a0 = ap[0], a1 = ap[1];
                float arow[DD] = {a0.x, a0.y, a0.z, a0.w, a1.x, a1.y, a1.z, a1.w};
#pragma unroll
                for (int j = 0; j < DD; ++j)
#pragma unroll
                    for (int m = 0; m < DD; ++m)
                        Ep[j][m] = fmaf(arow[j], tmp[i][m], Ep[j][m]);
            }
        }
#pragma unroll
        for (int i = 0; i < DD; ++i)
#pragma unroll
            for (int l = 0; l < DD; ++l) E[i][l] = Ep[i][l];
    }
    float diag = 0.0f;
#pragma unroll
    for (int i = 0; i < DD; ++i)
#pragma unroll
        for (int l = 0; l < DD; ++l) diag += (i * DD + l == lane) ? E[i][l] : 0.0f;
#pragma unroll
    for (int off = 32; off >= 1; off >>= 1) diag += __shfl_xor(diag, off, 64);
    if (lane == 0) {
        float tr = diag;
        out[2 * b]     = logf(fabsf(tr)) + 64.0f * 1.3862943611198906f;
        out[2 * b + 1] = (tr < 0.0f) ? 3.14159265358979323846f : 0.0f;
    }
}

extern "C" void kernel_launch(void* const* d_in, const int* in_sizes, int n_in,
                              void* d_out, int out_size, void* d_ws, size_t ws_size,
                              hipStream_t stream) {
    const int*   qn  = (const int*)d_in[0];
    const float* T   = (const float*)d_in[1];
    float*       out = (float*)d_out;
    const int B = in_sizes[0] / (2 * NSITES);
    const size_t WS_PAIR = (size_t)NPAIRS * 16 * 8 * 64 * 16;  // 4 MB
    if (ws_size >= WS_PAIR) {
        uint4* Mfp = (uint4*)d_ws;
        mpdo_prep2<<<dim3(NPAIRS * 16), dim3(64), 0, stream>>>(T, Mfp);
        mpdo_mfma8<<<dim3(B), dim3(512), 0, stream>>>(qn, Mfp, out);
    } else {
        mpdo_chain<<<dim3(B), dim3(64), 0, stream>>>(qn, T, out);
    }
}

// Round 7
// 43.705 us; speedup vs baseline: 1.0166x; 1.0166x over previous
//
#include <hip/hip_runtime.h>
#include <math.h>

// MPDO chain via MFMA + QUAD-product table.
//   per b: edge = Pi_t M_t (64x64), M_t = sum_k A_k (x) B_k; out = log(tr(edge))
//
// Ladder: R3 site table (64 steps, 42.5us) -> R5 pair table (32->16 steps/wave,
// 27us main) -> R7 quad table (16 steps, 1 wave/b). Chain-splitting across
// waves is null-to-negative (R4, R6); shortening the chain pays linearly.
//
//  * prep2both: per pair (32) x combo (16): P = M_even M_odd via Kron algebra,
//    stores BOTH (1/16)P^T and (1/16)P in bf16 MFMA-A-frag layout (4+4 MB).
//  * prep3: per quad (16) x combo (256): Q = P_e P_o via 16 MFMA
//    (A = Afrag(P_e), B-slot fed Afrag(P_o^T) => B-effective = P_o), then
//    verified make_Bf relayout => A-frag(Q^T), store (32 MB).
//  * main: R3 structure, 1 wave/b, 16 steps: X <- Q^T X; in-register C->B
//    relayout (cvt_pk_bf16 + permlane32_swap); trace; log.
//  * Scale: 1/16 per pair -> 1/256 per quad -> total 4^-64; log += 64*ln4.
// Fallback: ws < 40MB -> verified fp32 VALU kernel.

#define NSITES 64
#define NPAIRS 32
#define NQUADS 16

typedef short  s16x8  __attribute__((ext_vector_type(8)));
typedef float  f32x16 __attribute__((ext_vector_type(16)));

union Frag { unsigned int u[4]; s16x8 v; uint4 q; };

// B-frags (bf16) from acc (C-layout f32) — verified R3 relayout.
// Bf[ks][ct] = B-operand fragment; equivalently A-frag(W^T)[ct][ks] for W=acc.
__device__ __forceinline__ void make_Bf(const f32x16 acc[2][2], Frag Bf[4][2]) {
#pragma unroll
    for (int rt = 0; rt < 2; ++rt)
#pragma unroll
        for (int ct = 0; ct < 2; ++ct) {
            unsigned int w0[4], w1[4];
#pragma unroll
            for (int q = 0; q < 4; ++q) {
                asm("v_cvt_pk_bf16_f32 %0, %1, %2"
                    : "=v"(w0[q]) : "v"(acc[rt][ct][4 * q + 0]), "v"(acc[rt][ct][4 * q + 1]));
                asm("v_cvt_pk_bf16_f32 %0, %1, %2"
                    : "=v"(w1[q]) : "v"(acc[rt][ct][4 * q + 2]), "v"(acc[rt][ct][4 * q + 3]));
            }
#pragma unroll
            for (int kp = 0; kp < 2; ++kp) {
                unsigned int x0 = w0[2 * kp], y0 = w0[2 * kp + 1];
                asm("v_permlane32_swap_b32 %0, %1" : "+v"(x0), "+v"(y0));
                unsigned int x1 = w1[2 * kp], y1 = w1[2 * kp + 1];
                asm("v_permlane32_swap_b32 %0, %1" : "+v"(x1), "+v"(y1));
                Frag* f = &Bf[2 * rt + kp][ct];
                f->u[0] = x0; f->u[1] = x1; f->u[2] = y0; f->u[3] = y1;
            }
        }
}

// ---------- prep2both: (1/16)P^T and (1/16)P for all (pair, combo) ----------
__global__ __launch_bounds__(64)
void mpdo_prep2both(const float* __restrict__ T, uint4* __restrict__ MfpT,
                    uint4* __restrict__ MfpN) {
    const int blk = blockIdx.x;              // 32 pairs * 16 combos
    const int pair = blk >> 4, combo = blk & 15;
    const int c0 = combo >> 2, c1 = combo & 3;
    const int ir0 = c0 >> 1, ic0 = c0 & 1, ir1 = c1 >> 1, ic1 = c1 & 1;
    const int lane = threadIdx.x;
    const int site0 = 2 * pair, site1 = 2 * pair + 1;

    __shared__ float sT0[256], sT1[256], sT2[256], sT3[256];
    __shared__ float sPA[16 * 64], sPB[16 * 64];

    *(float4*)&sT0[lane * 4] = *(const float4*)(T + ((size_t)(site0 * 2 + ir0)) * 256 + lane * 4);
    *(float4*)&sT1[lane * 4] = *(const float4*)(T + ((size_t)(site0 * 2 + ic0)) * 256 + lane * 4);
    *(float4*)&sT2[lane * 4] = *(const float4*)(T + ((size_t)(site1 * 2 + ir1)) * 256 + lane * 4);
    *(float4*)&sT3[lane * 4] = *(const float4*)(T + ((size_t)(site1 * 2 + ic1)) * 256 + lane * 4);
    __syncthreads();

    {   // PA_c[i][j] = sum_a Tr0[i][a][k]*Tr1[a][j][jp]; PB analogous (conj cols)
        const int i = lane >> 3, j = lane & 7;
        float pa[4][4], pb[4][4];
#pragma unroll
        for (int k = 0; k < 4; ++k)
#pragma unroll
            for (int jp = 0; jp < 4; ++jp) { pa[k][jp] = 0.0f; pb[k][jp] = 0.0f; }
#pragma unroll
        for (int a = 0; a < 8; ++a) {
            float4 x0 = *(const float4*)&sT0[(i * 8 + a) * 4];
            float4 y0 = *(const float4*)&sT2[(a * 8 + j) * 4];
            float4 x1 = *(const float4*)&sT1[(i * 8 + a) * 4];
            float4 y1 = *(const float4*)&sT3[(a * 8 + j) * 4];
            const float xk0[4] = {x0.x, x0.y, x0.z, x0.w};
            const float yj0[4] = {y0.x, y0.y, y0.z, y0.w};
            const float xk1[4] = {x1.x, x1.y, x1.z, x1.w};
            const float yj1[4] = {y1.x, y1.y, y1.z, y1.w};
#pragma unroll
            for (int k = 0; k < 4; ++k)
#pragma unroll
                for (int jp = 0; jp < 4; ++jp) {
                    pa[k][jp] = fmaf(xk0[k], yj0[jp], pa[k][jp]);
                    pb[k][jp] = fmaf(xk1[k], yj1[jp], pb[k][jp]);
                }
        }
#pragma unroll
        for (int k = 0; k < 4; ++k)
#pragma unroll
            for (int jp = 0; jp < 4; ++jp) {
                sPA[(k * 4 + jp) * 64 + lane] = pa[k][jp];
                sPB[(k * 4 + jp) * 64 + lane] = pb[k][jp];
            }
    }
    __syncthreads();

    const int h = lane >> 5, r = lane & 31, m = r & 7, j2 = r >> 3;

    // ---- P^T table (verified R5 assembly) ----
    {
        float acc[8][8];
#pragma unroll
        for (int f = 0; f < 8; ++f)
#pragma unroll
            for (int e = 0; e < 8; ++e) acc[f][e] = 0.0f;
#pragma unroll 4
        for (int c = 0; c < 16; ++c) {
            float paf[8], pbe[8];
#pragma unroll
            for (int ti = 0; ti < 2; ++ti)
#pragma unroll
                for (int kt = 0; kt < 4; ++kt)
                    paf[ti * 4 + kt] = sPA[c * 64 + (2 * kt + h) * 8 + (4 * ti + j2)];
#pragma unroll
            for (int e = 0; e < 8; ++e) pbe[e] = sPB[c * 64 + e * 8 + m];
#pragma unroll
            for (int f = 0; f < 8; ++f)
#pragma unroll
                for (int e = 0; e < 8; ++e)
                    acc[f][e] = fmaf(paf[f], pbe[e], acc[f][e]);
        }
#pragma unroll
        for (int f = 0; f < 8; ++f) {
            unsigned int wds[4];
#pragma unroll
            for (int q = 0; q < 4; ++q) {
                float v0 = acc[f][2 * q]     * 0.0625f;
                float v1 = acc[f][2 * q + 1] * 0.0625f;
                asm("v_cvt_pk_bf16_f32 %0, %1, %2" : "=v"(wds[q]) : "v"(v0), "v"(v1));
            }
            MfpT[((size_t)(pair * 16 + combo) * 8 + f) * 64 + lane] =
                make_uint4(wds[0], wds[1], wds[2], wds[3]);
        }
    }

    // ---- P (non-transposed) table: A-frag(P) ----
    // W[32ti+r][16kt+8h+e] = P[p][q], p=32ti+r (i=4ti+(r>>3), l=r&7),
    // q=16kt+8h+e (j=2kt+h, m=e) => PA[4ti+(r>>3)][2kt+h] * PB[r&7][e]
    {
        float acc[8][8];
#pragma unroll
        for (int f = 0; f < 8; ++f)
#pragma unroll
            for (int e = 0; e < 8; ++e) acc[f][e] = 0.0f;
#pragma unroll 4
        for (int c = 0; c < 16; ++c) {
            float paf[8], pbe[8];
#pragma unroll
            for (int ti = 0; ti < 2; ++ti)
#pragma unroll
                for (int kt = 0; kt < 4; ++kt)
                    paf[ti * 4 + kt] = sPA[c * 64 + (4 * ti + j2) * 8 + (2 * kt + h)];
#pragma unroll
            for (int e = 0; e < 8; ++e) pbe[e] = sPB[c * 64 + m * 8 + e];
#pragma unroll
            for (int f = 0; f < 8; ++f)
#pragma unroll
                for (int e = 0; e < 8; ++e)
                    acc[f][e] = fmaf(paf[f], pbe[e], acc[f][e]);
        }
#pragma unroll
        for (int f = 0; f < 8; ++f) {
            unsigned int wds[4];
#pragma unroll
            for (int q = 0; q < 4; ++q) {
                float v0 = acc[f][2 * q]     * 0.0625f;
                float v1 = acc[f][2 * q + 1] * 0.0625f;
                asm("v_cvt_pk_bf16_f32 %0, %1, %2" : "=v"(wds[q]) : "v"(v0), "v"(v1));
            }
            MfpN[((size_t)(pair * 16 + combo) * 8 + f) * 64 + lane] =
                make_uint4(wds[0], wds[1], wds[2], wds[3]);
        }
    }
}

// ---------- prep3: quad table, A-frag(Q^T), Q = P_even * P_odd ----------
__global__ __launch_bounds__(64)
void mpdo_prep3(const uint4* __restrict__ MfpT, const uint4* __restrict__ MfpN,
                uint4* __restrict__ Mfq) {
    const int blk = blockIdx.x;              // u*256 + ce*16 + co
    const int u = blk >> 8, ce = (blk >> 4) & 15, co = blk & 15;
    const int lane = threadIdx.x;
    const int pe = 2 * u, po = 2 * u + 1;

    Frag Ae[2][4], Bo[4][2];
    const uint4* abase = MfpN + ((size_t)(pe * 16 + ce)) * 8 * 64 + lane;
#pragma unroll
    for (int ti = 0; ti < 2; ++ti)
#pragma unroll
        for (int kt = 0; kt < 4; ++kt)
            Ae[ti][kt].q = abase[(ti * 4 + kt) * 64];
    // pair-table frag f=tj*4+kt = A-frag(P_o^T)[tj][kt]; in B-slot => B-eff = P_o
    const uint4* bbase = MfpT + ((size_t)(po * 16 + co)) * 8 * 64 + lane;
#pragma unroll
    for (int kt = 0; kt < 4; ++kt)
#pragma unroll
        for (int tj = 0; tj < 2; ++tj)
            Bo[kt][tj].q = bbase[(tj * 4 + kt) * 64];

    f32x16 acc[2][2];
#pragma unroll
    for (int ti = 0; ti < 2; ++ti)
#pragma unroll
        for (int tj = 0; tj < 2; ++tj) {
            f32x16 d = {};
#pragma unroll
            for (int kt = 0; kt < 4; ++kt)
                d = __builtin_amdgcn_mfma_f32_32x32x16_bf16(Ae[ti][kt].v, Bo[kt][tj].v, d, 0, 0, 0);
            acc[ti][tj] = d;
        }

    // acc = Q (C-layout); make_Bf => B-frag(Q) = A-frag(Q^T):
    // main-loop frag (ti,kt) of A-frag(Q^T) == Bf[kt][ti]
    Frag Bf[4][2];
    make_Bf(acc, Bf);
    uint4* obase = Mfq + ((size_t)blk) * 8 * 64 + lane;
#pragma unroll
    for (int ti = 0; ti < 2; ++ti)
#pragma unroll
        for (int kt = 0; kt < 4; ++kt)
            obase[(ti * 4 + kt) * 64] = Bf[kt][ti].q;
}

// ---------- main: 1 wave per b, 16 quad-steps, X in MFMA accumulators ----------
__global__ __launch_bounds__(64, 1)
void mpdo_mfmaQ(const int* __restrict__ qn, const uint4* __restrict__ Mfq,
                float* __restrict__ out) {
    const int b = blockIdx.x;
    const int lane = threadIdx.x;
    const int* qb = qn + (size_t)b * (2 * NSITES);
    // lane u<16 holds 8-bit combo of quad u (sites 4u..4u+3)
    const int u = lane & 15, s = 4 * u;
    const int qq = (qb[s] << 7) | (qb[64 + s] << 6) | (qb[s + 1] << 5) | (qb[64 + s + 1] << 4) |
                   (qb[s + 2] << 3) | (qb[64 + s + 2] << 2) | (qb[s + 3] << 1) | qb[64 + s + 3];
    const int col = lane & 31, hh = lane >> 5;

    f32x16 acc[2][2];   // X, C-layout: row=32*rt+(g&3)+8*(g>>2)+4*hh, col=32*ct+col
#pragma unroll
    for (int rt = 0; rt < 2; ++rt)
#pragma unroll
        for (int ct = 0; ct < 2; ++ct)
#pragma unroll
            for (int g = 0; g < 16; ++g) {
                int row = (g & 3) + 8 * (g >> 2) + 4 * hh;
                acc[rt][ct][g] = (rt == ct && row == col) ? 1.0f : 0.0f;
            }

    Frag A0[2][4], A1[2][4];
    {
        int cfirst = __shfl(qq, 0, 64);
        const uint4* base = Mfq + ((size_t)cfirst) * 8 * 64 + lane;
#pragma unroll
        for (int ti = 0; ti < 2; ++ti)
#pragma unroll
            for (int kt = 0; kt < 4; ++kt)
                A0[ti][kt].q = base[(ti * 4 + kt) * 64];
    }

#define SITE_BODY(T_, CUR, NXT)                                               \
    {                                                                         \
        int tn = (T_) + 1; if (tn > 15) tn = 15;                              \
        int cn = __shfl(qq, tn, 64);                                          \
        const uint4* nbase = Mfq + ((size_t)(tn * 256 + cn)) * 8 * 64 + lane; \
        _Pragma("unroll")                                                     \
        for (int ti = 0; ti < 2; ++ti)                                        \
            _Pragma("unroll")                                                 \
            for (int kt = 0; kt < 4; ++kt)                                    \
                NXT[ti][kt].q = nbase[(ti * 4 + kt) * 64];                    \
        Frag Bf[4][2];                                                        \
        make_Bf(acc, Bf);                                                     \
        _Pragma("unroll")                                                     \
        for (int ti = 0; ti < 2; ++ti)                                        \
            _Pragma("unroll")                                                 \
            for (int tj = 0; tj < 2; ++tj) {                                  \
                f32x16 d = {};                                                \
                _Pragma("unroll")                                             \
                for (int kt = 0; kt < 4; ++kt)                                \
                    d = __builtin_amdgcn_mfma_f32_32x32x16_bf16(              \
                        CUR[ti][kt].v, Bf[kt][tj].v, d, 0, 0, 0);             \
                acc[ti][tj] = d;                                              \
            }                                                                 \
    }

#pragma unroll 1
    for (int t = 0; t < NQUADS; t += 2) {
        SITE_BODY(t,     A0, A1)
        SITE_BODY(t + 1, A1, A0)
    }
#undef SITE_BODY

    // trace of X (= full product transposed; trace invariant)
    float diag = 0.0f;
#pragma unroll
    for (int tt = 0; tt < 2; ++tt)
#pragma unroll
        for (int g = 0; g < 16; ++g) {
            int row = (g & 3) + 8 * (g >> 2) + 4 * hh;
            if (row == col) diag += acc[tt][tt][g];
        }
#pragma unroll
    for (int off = 32; off >= 1; off >>= 1)
        diag += __shfl_xor(diag, off, 64);

    if (lane == 0) {
        float tr = diag;
        float re = logf(fabsf(tr)) + 64.0f * 1.3862943611198906f;  // undo 4^-64
        float im = (tr < 0.0f) ? 3.14159265358979323846f : 0.0f;
        out[2 * b]     = re;
        out[2 * b + 1] = im;
    }
}

// ---------- fallback fp32 VALU kernel (verified R2) ----------
#define DD 8
#define KCHI 4
__global__ __launch_bounds__(64, 1)
void mpdo_chain(const int* __restrict__ qn, const float* __restrict__ T,
                float* __restrict__ out) {
    const int b = blockIdx.x;
    const int lane = threadIdx.x;
    __shared__ float sA[KCHI][DD][DD];
    __shared__ float sB[KCHI][DD][DD];
    float E[DD][DD];
#pragma unroll
    for (int i = 0; i < DD; ++i)
#pragma unroll
        for (int l = 0; l < DD; ++l) E[i][l] = (i * DD + l == lane) ? 1.0f : 0.0f;
    const int* qb = qn + (size_t)b * (2 * NSITES);
    int ir0 = qb[0], ic0 = qb[NSITES];
    float4 aP = *reinterpret_cast<const float4*>(T + (size_t)ir0 * 256 + lane * 4);
    float4 bP = *reinterpret_cast<const float4*>(T + (size_t)ic0 * 256 + lane * 4);
    const int li = lane >> 3, lj = lane & 7;
#pragma unroll 1
    for (int site = 0; site < NSITES; ++site) {
        __syncthreads();
        sA[0][li][lj] = 0.5f * aP.x; sA[1][li][lj] = 0.5f * aP.y;
        sA[2][li][lj] = 0.5f * aP.z; sA[3][li][lj] = 0.5f * aP.w;
        sB[0][li][lj] = 0.5f * bP.x; sB[1][li][lj] = 0.5f * bP.y;
        sB[2][li][lj] = 0.5f * bP.z; sB[3][li][lj] = 0.5f * bP.w;
        __syncthreads();
        if (site + 1 < NSITES) {
            int irn = qb[site + 1], icn = qb[NSITES + site + 1];
            aP = *reinterpret_cast<const float4*>(T + ((size_t)(site + 1) * 2 + irn) * 256 + lane * 4);
            bP = *reinterpret_cast<const float4*>(T + ((size_t)(site + 1) * 2 + icn) * 256 + lane * 4);
        }
        float Ep[DD][DD];
#pragma unroll
        for (int j = 0; j < DD; ++j)
#pragma unroll
            for (int m = 0; m < DD; ++m) Ep[j][m] = 0.0f;
#pragma unroll 1
        for (int k = 0; k < KCHI; ++k) {
            float tmp[DD][DD];
#pragma unroll
            for (int l = 0; l < DD; ++l) {
                const float4* bp = reinterpret_cast<const float4*>(&sB[k][l][0]);
                float4 b0 = bp[0], b1 = bp[1];
                float brow[DD] = {b0.x, b0.y, b0.z, b0.w, b1.x, b1.y, b1.z, b1.w};
                if (l == 0) {
#pragma unroll
                    for (int i = 0; i < DD; ++i)
#pragma unroll
                        for (int m = 0; m < DD; ++m) tmp[i][m] = E[i][0] * brow[m];
                } else {
#pragma unroll
                    for (int i = 0; i < DD; ++i)
#pragma unroll
                        for (int m = 0; m < DD; ++m)
                            tmp[i][m] = fmaf(E[i][l], brow[m], tmp[i][m]);
                }
            }
#pragma unroll
            for (int i = 0; i < DD; ++i) {
                const float4* ap = reinterpret_cast<const float4*>(&sA[k][i][0]);
                float4 a0 = ap[0], a1 = ap[1];
                float arow[DD] = {a0.x, a0.y, a0.z, a0.w, a1.x, a1.y, a1.z, a1.w};
#pragma unroll
                for (int j = 0; j < DD; ++j)
#pragma unroll
                    for (int m = 0; m < DD; ++m)
                        Ep[j][m] = fmaf(arow[j], tmp[i][m], Ep[j][m]);
            }
        }
#pragma unroll
        for (int i = 0; i < DD; ++i)
#pragma unroll
            for (int l = 0; l < DD; ++l) E[i][l] = Ep[i][l];
    }
    float diag = 0.0f;
#pragma unroll
    for (int i = 0; i < DD; ++i)
#pragma unroll
        for (int l = 0; l < DD; ++l) diag += (i * DD + l == lane) ? E[i][l] : 0.0f;
#pragma unroll
    for (int off = 32; off >= 1; off >>= 1) diag += __shfl_xor(diag, off, 64);
    if (lane == 0) {
        float tr = diag;
        out[2 * b]     = logf(fabsf(tr)) + 64.0f * 1.3862943611198906f;
        out[2 * b + 1] = (tr < 0.0f) ? 3.14159265358979323846f : 0.0f;
    }
}

extern "C" void kernel_launch(void* const* d_in, const int* in_sizes, int n_in,
                              void* d_out, int out_size, void* d_ws, size_t ws_size,
                              hipStream_t stream) {
    const int*   qn  = (const int*)d_in[0];
    const float* T   = (const float*)d_in[1];
    float*       out = (float*)d_out;
    const int B = in_sizes[0] / (2 * NSITES);
    const size_t SZ_PAIR = (size_t)NPAIRS * 16 * 8 * 64 * 16;   // 4 MB per table
    const size_t SZ_QUAD = (size_t)NQUADS * 256 * 8 * 64 * 16;  // 32 MB
    if (ws_size >= 2 * SZ_PAIR + SZ_QUAD) {
        uint4* MfpT = (uint4*)d_ws;                              // A-frag(P^T)
        uint4* MfpN = (uint4*)((char*)d_ws + SZ_PAIR);           // A-frag(P)
        uint4* Mfq  = (uint4*)((char*)d_ws + 2 * SZ_PAIR);       // A-frag(Q^T)
        mpdo_prep2both<<<dim3(NPAIRS * 16), dim3(64), 0, stream>>>(T, MfpT, MfpN);
        mpdo_prep3<<<dim3(NQUADS * 256), dim3(64), 0, stream>>>(MfpT, MfpN, Mfq);
        mpdo_mfmaQ<<<dim3(B), dim3(64), 0, stream>>>(qn, Mfq, out);
    } else {
        mpdo_chain<<<dim3(B), dim3(64), 0, stream>>>(qn, T, out);
    }
}

// Round 8
// 31.778 us; speedup vs baseline: 1.3982x; 1.3753x over previous
//
#include <hip/hip_runtime.h>
#include <math.h>

// MPDO chain via MFMA + PAIR-product table (L2-resident tier).
//   per b: edge = Pi_t M_t (64x64), M_t = sum_k A_k (x) B_k; out = log(tr(edge))
//
// Ladder: R3 site table 64 steps (42.5us) -> R5 pair table (31.9us) ->
// R7 quad table REGRESSED (32MB > 4MB XCD L2 -> refetch ~256MB ~ 40us).
// Table must stay L2-resident: pair tier (4MB) is the ceiling.
// Wave-splitting is null-to-negative (R4/R6): step-slots per SIMD cost
// ~constant; so R8 = 1 wave/b, 32 steps, and CUT PER-STEP ISSUE WORK:
//   * persistent zero f32x16 as first MFMA C operand; accumulate directly
//     into acc (make_Bf already consumed it) -> no 64x v_mov zero-init/copy
//   * readfirstlane scalar table base + per-lane offsets precomputed once
//     -> per-step address math is SALU-only
//   * depth-2 prefetch (A0/A1/A2 rotation) covers L2 latency
// Scale: 1/16 per pair -> 4^-64 total; log += 64*ln4.
// Fallback: ws < 4MB -> verified fp32 VALU kernel.

#define NSITES 64
#define NPAIRS 32

typedef short  s16x8  __attribute__((ext_vector_type(8)));
typedef float  f32x16 __attribute__((ext_vector_type(16)));

union Frag { unsigned int u[4]; s16x8 v; uint4 q; };

// ---------- prep2: (1/16)*P^T for all (pair, combo) — verified R5 ----------
__global__ __launch_bounds__(64)
void mpdo_prep2(const float* __restrict__ T, uint4* __restrict__ Mfp) {
    const int blk = blockIdx.x;              // 32 pairs * 16 combos
    const int pair = blk >> 4, combo = blk & 15;
    const int c0 = combo >> 2, c1 = combo & 3;
    const int ir0 = c0 >> 1, ic0 = c0 & 1, ir1 = c1 >> 1, ic1 = c1 & 1;
    const int lane = threadIdx.x;
    const int site0 = 2 * pair, site1 = 2 * pair + 1;

    __shared__ float sT0[256], sT1[256], sT2[256], sT3[256];
    __shared__ float sPA[16 * 64], sPB[16 * 64];

    *(float4*)&sT0[lane * 4] = *(const float4*)(T + ((size_t)(site0 * 2 + ir0)) * 256 + lane * 4);
    *(float4*)&sT1[lane * 4] = *(const float4*)(T + ((size_t)(site0 * 2 + ic0)) * 256 + lane * 4);
    *(float4*)&sT2[lane * 4] = *(const float4*)(T + ((size_t)(site1 * 2 + ir1)) * 256 + lane * 4);
    *(float4*)&sT3[lane * 4] = *(const float4*)(T + ((size_t)(site1 * 2 + ic1)) * 256 + lane * 4);
    __syncthreads();

    {
        const int i = lane >> 3, j = lane & 7;
        float pa[4][4], pb[4][4];
#pragma unroll
        for (int k = 0; k < 4; ++k)
#pragma unroll
            for (int jp = 0; jp < 4; ++jp) { pa[k][jp] = 0.0f; pb[k][jp] = 0.0f; }
#pragma unroll
        for (int a = 0; a < 8; ++a) {
            float4 x0 = *(const float4*)&sT0[(i * 8 + a) * 4];
            float4 y0 = *(const float4*)&sT2[(a * 8 + j) * 4];
            float4 x1 = *(const float4*)&sT1[(i * 8 + a) * 4];
            float4 y1 = *(const float4*)&sT3[(a * 8 + j) * 4];
            const float xk0[4] = {x0.x, x0.y, x0.z, x0.w};
            const float yj0[4] = {y0.x, y0.y, y0.z, y0.w};
            const float xk1[4] = {x1.x, x1.y, x1.z, x1.w};
            const float yj1[4] = {y1.x, y1.y, y1.z, y1.w};
#pragma unroll
            for (int k = 0; k < 4; ++k)
#pragma unroll
                for (int jp = 0; jp < 4; ++jp) {
                    pa[k][jp] = fmaf(xk0[k], yj0[jp], pa[k][jp]);
                    pb[k][jp] = fmaf(xk1[k], yj1[jp], pb[k][jp]);
                }
        }
#pragma unroll
        for (int k = 0; k < 4; ++k)
#pragma unroll
            for (int jp = 0; jp < 4; ++jp) {
                sPA[(k * 4 + jp) * 64 + lane] = pa[k][jp];
                sPB[(k * 4 + jp) * 64 + lane] = pb[k][jp];
            }
    }
    __syncthreads();

    const int h = lane >> 5, r = lane & 31, m = r & 7, j2 = r >> 3;
    float acc[8][8];
#pragma unroll
    for (int f = 0; f < 8; ++f)
#pragma unroll
        for (int e = 0; e < 8; ++e) acc[f][e] = 0.0f;

#pragma unroll 4
    for (int c = 0; c < 16; ++c) {
        float paf[8], pbe[8];
#pragma unroll
        for (int ti = 0; ti < 2; ++ti)
#pragma unroll
            for (int kt = 0; kt < 4; ++kt)
                paf[ti * 4 + kt] = sPA[c * 64 + (2 * kt + h) * 8 + (4 * ti + j2)];
#pragma unroll
        for (int e = 0; e < 8; ++e) pbe[e] = sPB[c * 64 + e * 8 + m];
#pragma unroll
        for (int f = 0; f < 8; ++f)
#pragma unroll
            for (int e = 0; e < 8; ++e)
                acc[f][e] = fmaf(paf[f], pbe[e], acc[f][e]);
    }

#pragma unroll
    for (int f = 0; f < 8; ++f) {
        unsigned int wds[4];
#pragma unroll
        for (int q = 0; q < 4; ++q) {
            float v0 = acc[f][2 * q]     * 0.0625f;
            float v1 = acc[f][2 * q + 1] * 0.0625f;
            asm("v_cvt_pk_bf16_f32 %0, %1, %2" : "=v"(wds[q]) : "v"(v0), "v"(v1));
        }
        Mfp[((size_t)(pair * 16 + combo) * 8 + f) * 64 + lane] =
            make_uint4(wds[0], wds[1], wds[2], wds[3]);
    }
}

// ---------- main: 1 wave per b, 32 pair-steps, lean inner loop ----------
__global__ __launch_bounds__(64, 1)
void mpdo_mfmaP1(const int* __restrict__ qn, const uint4* __restrict__ Mfp,
                 float* __restrict__ out) {
    const int b = blockIdx.x;
    const int lane = threadIdx.x;
    const int* qb = qn + (size_t)b * (2 * NSITES);
    // lane p<32 holds combo of pair p
    const int pi = lane & 31;
    const int pc = (qb[2 * pi] << 3) | (qb[64 + 2 * pi] << 2) |
                   (qb[2 * pi + 1] << 1) | (qb[64 + 2 * pi + 1]);
    const int col = lane & 31, hh = lane >> 5;

    // per-lane byte offsets into a table entry (constant across steps)
    const size_t laneoff = (size_t)lane * 16;

    f32x16 acc[2][2];   // X, C-layout
#pragma unroll
    for (int rt = 0; rt < 2; ++rt)
#pragma unroll
        for (int ct = 0; ct < 2; ++ct)
#pragma unroll
            for (int g = 0; g < 16; ++g) {
                int row = (g & 3) + 8 * (g >> 2) + 4 * hh;
                acc[rt][ct][g] = (rt == ct && row == col) ? 1.0f : 0.0f;
            }

    const f32x16 zc = {};   // persistent zero C-operand (never written)

    Frag A0[2][4], A1[2][4], A2[2][4];
#define LOAD_FRAGS(DST, PIDX)                                                  \
    {                                                                          \
        int c_ = __builtin_amdgcn_readfirstlane(__shfl(pc, (PIDX), 64));       \
        const char* nb_ = (const char*)Mfp +                                   \
            (((size_t)(PIDX) * 16 + c_) * 8 * 64) * 16 + laneoff;              \
        _Pragma("unroll")                                                      \
        for (int ti = 0; ti < 2; ++ti)                                         \
            _Pragma("unroll")                                                  \
            for (int kt = 0; kt < 4; ++kt)                                     \
                DST[ti][kt].q = *(const uint4*)(nb_ + (ti * 4 + kt) * 1024);   \
    }

    LOAD_FRAGS(A0, 0)
    LOAD_FRAGS(A1, 1)

#define SITE_BODY(T_, CUR, NXT)                                               \
    {                                                                         \
        int tn = (T_) + 2; if (tn > 31) tn = 31;                              \
        LOAD_FRAGS(NXT, tn)                                                   \
        Frag Bf[4][2];                                                        \
        _Pragma("unroll")                                                     \
        for (int rt = 0; rt < 2; ++rt)                                        \
            _Pragma("unroll")                                                 \
            for (int ct = 0; ct < 2; ++ct) {                                  \
                unsigned int w0[4], w1[4];                                    \
                _Pragma("unroll")                                             \
                for (int q = 0; q < 4; ++q) {                                 \
                    asm("v_cvt_pk_bf16_f32 %0, %1, %2"                        \
                        : "=v"(w0[q])                                         \
                        : "v"(acc[rt][ct][4 * q + 0]),                        \
                          "v"(acc[rt][ct][4 * q + 1]));                       \
                    asm("v_cvt_pk_bf16_f32 %0, %1, %2"                        \
                        : "=v"(w1[q])                                         \
                        : "v"(acc[rt][ct][4 * q + 2]),                        \
                          "v"(acc[rt][ct][4 * q + 3]));                       \
                }                                                             \
                _Pragma("unroll")                                             \
                for (int kp = 0; kp < 2; ++kp) {                              \
                    unsigned int x0 = w0[2 * kp], y0 = w0[2 * kp + 1];        \
                    asm("v_permlane32_swap_b32 %0, %1" : "+v"(x0), "+v"(y0)); \
                    unsigned int x1 = w1[2 * kp], y1 = w1[2 * kp + 1];        \
                    asm("v_permlane32_swap_b32 %0, %1" : "+v"(x1), "+v"(y1)); \
                    Frag* f = &Bf[2 * rt + kp][ct];                           \
                    f->u[0] = x0; f->u[1] = x1; f->u[2] = y0; f->u[3] = y1;   \
                }                                                             \
            }                                                                 \
        /* acc consumed by Bf; accumulate new product directly into acc */    \
        _Pragma("unroll")                                                     \
        for (int ti = 0; ti < 2; ++ti)                                        \
            _Pragma("unroll")                                                 \
            for (int tj = 0; tj < 2; ++tj) {                                  \
                f32x16 d = __builtin_amdgcn_mfma_f32_32x32x16_bf16(           \
                    CUR[ti][0].v, Bf[0][tj].v, zc, 0, 0, 0);                  \
                _Pragma("unroll")                                             \
                for (int kt = 1; kt < 4; ++kt)                                \
                    d = __builtin_amdgcn_mfma_f32_32x32x16_bf16(              \
                        CUR[ti][kt].v, Bf[kt][tj].v, d, 0, 0, 0);             \
                acc[ti][tj] = d;                                              \
            }                                                                 \
    }

#pragma unroll 1
    for (int t = 0; t < 30; t += 3) {
        SITE_BODY(t,     A0, A2)
        SITE_BODY(t + 1, A1, A0)
        SITE_BODY(t + 2, A2, A1)
    }
    SITE_BODY(30, A0, A2)   // tail prefetches clamp to pair 31 (discarded)
    SITE_BODY(31, A1, A0)
#undef SITE_BODY
#undef LOAD_FRAGS

    // trace (X = full product transposed; trace invariant)
    float diag = 0.0f;
#pragma unroll
    for (int tt = 0; tt < 2; ++tt)
#pragma unroll
        for (int g = 0; g < 16; ++g) {
            int row = (g & 3) + 8 * (g >> 2) + 4 * hh;
            if (row == col) diag += acc[tt][tt][g];
        }
#pragma unroll
    for (int off = 32; off >= 1; off >>= 1)
        diag += __shfl_xor(diag, off, 64);

    if (lane == 0) {
        float tr = diag;
        float re = logf(fabsf(tr)) + 64.0f * 1.3862943611198906f;  // undo 4^-64
        float im = (tr < 0.0f) ? 3.14159265358979323846f : 0.0f;
        out[2 * b]     = re;
        out[2 * b + 1] = im;
    }
}

// ---------- fallback fp32 VALU kernel (verified R2) ----------
#define DD 8
#define KCHI 4
__global__ __launch_bounds__(64, 1)
void mpdo_chain(const int* __restrict__ qn, const float* __restrict__ T,
                float* __restrict__ out) {
    const int b = blockIdx.x;
    const int lane = threadIdx.x;
    __shared__ float sA[KCHI][DD][DD];
    __shared__ float sB[KCHI][DD][DD];
    float E[DD][DD];
#pragma unroll
    for (int i = 0; i < DD; ++i)
#pragma unroll
        for (int l = 0; l < DD; ++l) E[i][l] = (i * DD + l == lane) ? 1.0f : 0.0f;
    const int* qb = qn + (size_t)b * (2 * NSITES);
    int ir0 = qb[0], ic0 = qb[NSITES];
    float4 aP = *reinterpret_cast<const float4*>(T + (size_t)ir0 * 256 + lane * 4);
    float4 bP = *reinterpret_cast<const float4*>(T + (size_t)ic0 * 256 + lane * 4);
    const int li = lane >> 3, lj = lane & 7;
#pragma unroll 1
    for (int site = 0; site < NSITES; ++site) {
        __syncthreads();
        sA[0][li][lj] = 0.5f * aP.x; sA[1][li][lj] = 0.5f * aP.y;
        sA[2][li][lj] = 0.5f * aP.z; sA[3][li][lj] = 0.5f * aP.w;
        sB[0][li][lj] = 0.5f * bP.x; sB[1][li][lj] = 0.5f * bP.y;
        sB[2][li][lj] = 0.5f * bP.z; sB[3][li][lj] = 0.5f * bP.w;
        __syncthreads();
        if (site + 1 < NSITES) {
            int irn = qb[site + 1], icn = qb[NSITES + site + 1];
            aP = *reinterpret_cast<const float4*>(T + ((size_t)(site + 1) * 2 + irn) * 256 + lane * 4);
            bP = *reinterpret_cast<const float4*>(T + ((size_t)(site + 1) * 2 + icn) * 256 + lane * 4);
        }
        float Ep[DD][DD];
#pragma unroll
        for (int j = 0; j < DD; ++j)
#pragma unroll
            for (int m = 0; m < DD; ++m) Ep[j][m] = 0.0f;
#pragma unroll 1
        for (int k = 0; k < KCHI; ++k) {
            float tmp[DD][DD];
#pragma unroll
            for (int l = 0; l < DD; ++l) {
                const float4* bp = reinterpret_cast<const float4*>(&sB[k][l][0]);
                float4 b0 = bp[0], b1 = bp[1];
                float brow[DD] = {b0.x, b0.y, b0.z, b0.w, b1.x, b1.y, b1.z, b1.w};
                if (l == 0) {
#pragma unroll
                    for (int i = 0; i < DD; ++i)
#pragma unroll
                        for (int m = 0; m < DD; ++m) tmp[i][m] = E[i][0] * brow[m];
                } else {
#pragma unroll
                    for (int i = 0; i < DD; ++i)
#pragma unroll
                        for (int m = 0; m < DD; ++m)
                            tmp[i][m] = fmaf(E[i][l], brow[m], tmp[i][m]);
                }
            }
#pragma unroll
            for (int i = 0; i < DD; ++i) {
                const float4* ap = reinterpret_cast<const float4*>(&sA[k][i][0]);
                float4 a0 = ap[0], a1 = ap[1];
                float arow[DD] = {a0.x, a0.y, a0.z, a0.w, a1.x, a1.y, a1.z, a1.w};
#pragma unroll
                for (int j = 0; j < DD; ++j)
#pragma unroll
                    for (int m = 0; m < DD; ++m)
                        Ep[j][m] = fmaf(arow[j], tmp[i][m], Ep[j][m]);
            }
        }
#pragma unroll
        for (int i = 0; i < DD; ++i)
#pragma unroll
            for (int l = 0; l < DD; ++l) E[i][l] = Ep[i][l];
    }
    float diag = 0.0f;
#pragma unroll
    for (int i = 0; i < DD; ++i)
#pragma unroll
        for (int l = 0; l < DD; ++l) diag += (i * DD + l == lane) ? E[i][l] : 0.0f;
#pragma unroll
    for (int off = 32; off >= 1; off >>= 1) diag += __shfl_xor(diag, off, 64);
    if (lane == 0) {
        float tr = diag;
        out[2 * b]     = logf(fabsf(tr)) + 64.0f * 1.3862943611198906f;
        out[2 * b + 1] = (tr < 0.0f) ? 3.14159265358979323846f : 0.0f;
    }
}

extern "C" void kernel_launch(void* const* d_in, const int* in_sizes, int n_in,
                              void* d_out, int out_size, void* d_ws, size_t ws_size,
                              hipStream_t stream) {
    const int*   qn  = (const int*)d_in[0];
    const float* T   = (const float*)d_in[1];
    float*       out = (float*)d_out;
    const int B = in_sizes[0] / (2 * NSITES);
    const size_t WS_PAIR = (size_t)NPAIRS * 16 * 8 * 64 * 16;  // 4 MB
    if (ws_size >= WS_PAIR) {
        uint4* Mfp = (uint4*)d_ws;
        mpdo_prep2<<<dim3(NPAIRS * 16), dim3(64), 0, stream>>>(T, Mfp);
        mpdo_mfmaP1<<<dim3(B), dim3(64), 0, stream>>>(qn, Mfp, out);
    } else {
        mpdo_chain<<<dim3(B), dim3(64), 0, stream>>>(qn, T, out);
    }
}